// Round 1
// 21711.217 us; speedup vs baseline: 1.3829x; 1.3829x over previous
//
#include <hip/hip_runtime.h>
#include <math.h>

#define V    50257
#define E    512
#define H    1024
#define S    128
#define BS   8
#define T    64
#define SOS  1
#define EOS  2
#define NEGV (-1e9f)
#define H3   (3*H)
#define KS   16
#define RPK  ((E+H)/KS)   // 96
#define TKCH 6283         // 8*6283 = 50264 >= V
#define CB   197          // col-blocks for gemv: 197*256 = 50432 >= V

// ---------------- ws-size marker kernels (rocprof introspection, no-ops) ----------------
__global__ void k_ws_ge_032mb() {}
__global__ void k_ws_ge_064mb() {}
__global__ void k_ws_ge_128mb() {}
__global__ void k_ws_ge_210mb() {}
__global__ void k_ws_ge_256mb() {}
__global__ void k_ws_ge_384mb() {}
__global__ void k_ws_ge_512mb() {}

// ---------------- init ----------------
__global__ void k_init(const float* __restrict__ h0, float* h, float* cum,
                       int* len, int* fin, int* lat, int* tok) {
    int t = threadIdx.x;
    for (int i = t; i < BS*H; i += 256) h[i] = h0[i % H];
    for (int i = t; i < BS*T; i += 256) tok[i] = 0;
    if (t < BS) { cum[t] = 0.f; len[t] = 1; fin[t] = 0; lat[t] = SOS; }
}

// ---------------- GRU partials (split-K, deterministic) ----------------
__global__ __launch_bounds__(256) void k_gru_part(
    const float* __restrict__ emb, const float* __restrict__ Wx,
    const float* __restrict__ Wh, const float* __restrict__ h,
    const int* __restrict__ lat, float* __restrict__ part)
{
    int jb = blockIdx.x;        // 0..3
    int k  = blockIdx.y;        // 0..KS-1
    int t  = threadIdx.x;
    int j  = jb*256 + t;
    int c0 = k * RPK;
    __shared__ float vals[RPK*BS];
    for (int m = t; m < RPK*8; m += 256) {
        int c = c0 + (m >> 3);
        int b = m & 7;
        float v;
        if (c < E) v = emb[(size_t)lat[b]*E + c];
        else       v = h[b*H + (c - E)];
        vals[m] = v;
    }
    __syncthreads();
    float pz[BS] = {0}, pr[BS] = {0}, pnx[BS] = {0}, pnh[BS] = {0};
    for (int cc = 0; cc < RPK; ++cc) {
        int c = c0 + cc;
        bool isx = (c < E);
        const float* Wrow = isx ? (Wx + (size_t)c*H3) : (Wh + (size_t)(c-E)*H3);
        float wz = Wrow[j];
        float wr = Wrow[j + H];
        float wn = Wrow[j + 2*H];
        #pragma unroll
        for (int b = 0; b < BS; ++b) {
            float v = vals[cc*8 + b];
            pz[b] += v * wz;
            pr[b] += v * wr;
            if (isx) pnx[b] += v * wn; else pnh[b] += v * wn;
        }
    }
    #pragma unroll
    for (int b = 0; b < BS; ++b) {
        part[(((size_t)k*4 + 0)*8 + b)*H + j] = pz[b];
        part[(((size_t)k*4 + 1)*8 + b)*H + j] = pr[b];
        part[(((size_t)k*4 + 2)*8 + b)*H + j] = pnx[b];
        part[(((size_t)k*4 + 3)*8 + b)*H + j] = pnh[b];
    }
}

// ---------------- fused: gate reduce + attention (one block per beam) ----------------
__global__ __launch_bounds__(256) void k_gate_attn(
    const float* __restrict__ part, const float* __restrict__ h,
    const float* __restrict__ enc, float* __restrict__ hcT)
{
    int b = blockIdx.x;
    int t = threadIdx.x;
    __shared__ float hn[H];
    __shared__ float att[S];
    __shared__ float smax, ssum;
    for (int j = t; j < H; j += 256) {
        float pz = 0.f, pr = 0.f, pnx = 0.f, pnh = 0.f;
        #pragma unroll
        for (int k = 0; k < KS; ++k) {
            pz  += part[(((size_t)k*4 + 0)*8 + b)*H + j];
            pr  += part[(((size_t)k*4 + 1)*8 + b)*H + j];
            pnx += part[(((size_t)k*4 + 2)*8 + b)*H + j];
            pnh += part[(((size_t)k*4 + 3)*8 + b)*H + j];
        }
        float z = 1.f / (1.f + expf(-pz));
        float r = 1.f / (1.f + expf(-pr));
        float n = tanhf(pnx + r * pnh);
        float v = (1.f - z) * n + z * h[b*H + j];
        hn[j] = v;
        hcT[(size_t)j*8 + b] = v;
    }
    __syncthreads();
    int wave = t >> 6, lane = t & 63;
    for (int s = wave; s < S; s += 4) {
        float acc = 0.f;
        #pragma unroll 4
        for (int hh = lane; hh < H; hh += 64)
            acc += hn[hh] * enc[(size_t)s*H + hh];
        #pragma unroll
        for (int off = 32; off; off >>= 1) acc += __shfl_down(acc, off, 64);
        if (lane == 0) att[s] = acc;
    }
    __syncthreads();
    if (t == 0) {
        float m = -3.0e38f;
        for (int s = 0; s < S; ++s) m = fmaxf(m, att[s]);
        smax = m;
    }
    __syncthreads();
    if (t < S) att[t] = expf(att[t] - smax);
    __syncthreads();
    if (t == 0) {
        float sum = 0.f;
        for (int s = 0; s < S; ++s) sum += att[s];
        ssum = sum;
    }
    __syncthreads();
    if (t < S) att[t] = att[t] / ssum;
    __syncthreads();
    for (int j = t; j < H; j += 256) {
        float acc = 0.f;
        for (int s = 0; s < S; ++s) acc += att[s] * enc[(size_t)s*H + j];
        hcT[(size_t)(H + j)*8 + b] = acc;
    }
}

// ---------------- fp32 logits partial GEMV: high-occupancy row-split ----------------
// Bit-identical per-element to the old k_logits_part (same ascending-row fma chain,
// same lpart layout), but 1576 blocks instead of 400 and no 8x256-col register tile.
__global__ __launch_bounds__(256) void k_gemv_part(
    const float* __restrict__ Wout, const float* __restrict__ hcT,
    float* __restrict__ lpart)
{
    int t  = threadIdx.x;
    int rs = blockIdx.y;             // 0..7 (256-row split)
    int r0 = rs * 256;
    int c  = blockIdx.x * 256 + t;   // 0..50431
    __shared__ float hc[256*8];
    for (int m = t; m < 256*8; m += 256) hc[m] = hcT[(size_t)r0*8 + m];
    __syncthreads();
    int cl = (c < V) ? c : (V - 1);
    const float* wp = Wout + (size_t)r0*V + cl;
    float a[8] = {0,0,0,0,0,0,0,0};
    #pragma unroll 8
    for (int rr = 0; rr < 256; ++rr) {
        float w = wp[(size_t)rr*V];
        const float* hr = hc + rr*8;
        #pragma unroll
        for (int b = 0; b < 8; ++b) a[b] += hr[b] * w;
    }
    if (c < V) {
        #pragma unroll
        for (int b = 0; b < 8; ++b)
            lpart[((size_t)rs*8 + b)*V + c] = a[b];
    }
}

// ---------------- per-(beam,chunk): top-8 + lse partials (verified structure) ----------------
__global__ __launch_bounds__(256) void k_topk_part(
    const float* __restrict__ lpart, const float* __restrict__ bout,
    float* __restrict__ cand_v, int* __restrict__ cand_i,
    float* __restrict__ cm, float* __restrict__ clp)
{
    int b = blockIdx.x, c = blockIdx.y, t = threadIdx.x;
    int vstart = c * TKCH;
    int vend = (vstart + TKCH < V) ? (vstart + TKCH) : V;
    float bv[8]; int bi[8];
    #pragma unroll
    for (int r = 0; r < 8; ++r) { bv[r] = -3.0e38f; bi[r] = 0x7fffffff; }
    float m = -3.0e38f, l = 0.f;
    for (int v = vstart + t; v < vend; v += 256) {
        float x = bout[v];
        #pragma unroll
        for (int r = 0; r < 8; ++r)
            x += lpart[((size_t)r*8 + b)*V + v];
        if (x > m) { l = l * expf(m - x) + 1.f; m = x; }
        else         l += expf(x - m);
        if (x > bv[7]) {
            bv[7] = x; bi[7] = v;
            #pragma unroll
            for (int q = 7; q > 0; --q) {
                if (bv[q] > bv[q-1]) {
                    float tv = bv[q]; bv[q] = bv[q-1]; bv[q-1] = tv;
                    int   ti = bi[q]; bi[q] = bi[q-1]; bi[q-1] = ti;
                }
            }
        }
    }
    __shared__ float pm[256], pl[256];
    pm[t] = m; pl[t] = l;
    __syncthreads();
    for (int off = 128; off; off >>= 1) {
        if (t < off) {
            float m2 = pm[t+off], l2 = pl[t+off];
            float M = fmaxf(pm[t], m2);
            pl[t] = pl[t]*expf(pm[t]-M) + l2*expf(m2-M);
            pm[t] = M;
        }
        __syncthreads();
    }
    if (t == 0) { cm[b*8 + c] = pm[0]; clp[b*8 + c] = pl[0]; }

    __shared__ float pv[2048];
    __shared__ int   pi[2048];
    __shared__ float rv[256];
    __shared__ int   ri[256], rp[256];
    #pragma unroll
    for (int r = 0; r < 8; ++r) { pv[t*8+r] = bv[r]; pi[t*8+r] = bi[r]; }
    __syncthreads();
    for (int round = 0; round < 8; ++round) {
        float lv = -3.0e38f; int li = 0x7fffffff, lp = -1;
        #pragma unroll
        for (int r = 0; r < 8; ++r) {
            float v2 = pv[t*8+r]; int i2 = pi[t*8+r];
            if (v2 > lv || (v2 == lv && i2 < li)) { lv = v2; li = i2; lp = t*8+r; }
        }
        rv[t] = lv; ri[t] = li; rp[t] = lp;
        __syncthreads();
        for (int off = 128; off; off >>= 1) {
            if (t < off) {
                if (rv[t+off] > rv[t] || (rv[t+off] == rv[t] && ri[t+off] < ri[t])) {
                    rv[t] = rv[t+off]; ri[t] = ri[t+off]; rp[t] = rp[t+off];
                }
            }
            __syncthreads();
        }
        if (t == 0) {
            cand_v[(b*8 + c)*8 + round] = rv[0];
            cand_i[(b*8 + c)*8 + round] = ri[0];
            pv[rp[0]] = -3.0e38f; pi[rp[0]] = 0x7fffffff;
        }
        __syncthreads();
    }
}

// ---------------- merge 8x8 candidates + lse + beam update (register bitmasks) ----------------
__global__ __launch_bounds__(256) void k_merge_update_fb(
    const float* __restrict__ cand_v, const int* __restrict__ cand_i,
    const float* __restrict__ cm, const float* __restrict__ clp,
    const float* cum_i, const int* len_i, const int* fin_i,
    const int* lat_i, const int* tok_i,
    float* cum_o, int* len_o, int* fin_o, int* lat_o, int* tok_o,
    const float* __restrict__ hcT, float* __restrict__ h, int step)
{
    int t = threadIdx.x;
    __shared__ float cv[512];
    __shared__ int   ci[512];
    __shared__ float t8v[64];
    __shared__ int   t8i[64];
    __shared__ float lse[8];
    for (int i = t; i < 512; i += 256) { cv[i] = cand_v[i]; ci[i] = cand_i[i]; }
    __syncthreads();
    if (t < 8) {
        int b = t;
        float m = -3.0e38f, l = 0.f;
        for (int c = 0; c < 8; ++c) {
            float m2 = cm[b*8 + c], l2 = clp[b*8 + c];
            float M = fmaxf(m, m2);
            l = l*expf(m - M) + l2*expf(m2 - M);
            m = M;
        }
        lse[b] = m + logf(l);
        unsigned long long tk = 0ull;
        for (int round = 0; round < 8; ++round) {
            float bvv = -3.4e38f; int bii = 0x7fffffff, bp = 0;
            for (int i = 0; i < 64; ++i) {
                if ((tk >> i) & 1ull) continue;
                float v2 = cv[b*64 + i]; int i2 = ci[b*64 + i];
                if (v2 > bvv || (v2 == bvv && i2 < bii)) { bvv = v2; bii = i2; bp = i; }
            }
            tk |= 1ull << bp;
            t8v[b*8 + round] = bvv;
            t8i[b*8 + round] = bii;
        }
    }
    __syncthreads();

    __shared__ float flat[64];
    __shared__ float ccum[64];
    __shared__ int   clen[64];
    __shared__ int   sel[8];
    if (t < 64) {
        int b = t >> 3, j = t & 7;
        int alive = fin_i[b] ? 0 : 1;
        float lp = t8v[b*8 + j] - lse[b];
        float cc = cum_i[b] + (alive ? lp : 0.f);
        int   cln = len_i[b] + alive;
        float score = cc / (float)cln;
        bool valid = (alive || j == 0) && ((step > 0) || (b == 0));
        flat[t] = valid ? score : NEGV;
        ccum[t] = cc; clen[t] = cln;
    }
    __syncthreads();
    if (t == 0) {
        unsigned long long tk = 0ull;
        for (int r = 0; r < 8; ++r) {
            float bestv = -3.4e38f; int bidx = 0;
            for (int i = 0; i < 64; ++i) {
                if (!((tk >> i) & 1ull) && flat[i] > bestv) { bestv = flat[i]; bidx = i; }
            }
            tk |= 1ull << bidx; sel[r] = bidx;
        }
    }
    __syncthreads();
    if (t < 8) {
        int idx = sel[t];
        int parent = idx >> 3, child = idx & 7;
        int p_fin = fin_i[parent];
        int new_tok = t8i[parent*8 + child];
        cum_o[t] = ccum[idx];
        len_o[t] = clen[idx];
        fin_o[t] = (p_fin || new_tok == EOS) ? 1 : 0;
        lat_o[t] = p_fin ? lat_i[parent] : new_tok;
    }
    __syncthreads();
    for (int m = t; m < BS*T; m += 256) {
        int nb = m / T, pos = m % T;
        int idx = sel[nb];
        int parent = idx >> 3, child = idx & 7;
        int p_fin = fin_i[parent];
        int p_len = len_i[parent];
        int new_tok = t8i[parent*8 + child];
        int val = tok_i[parent*T + pos];
        if (pos == p_len - 1 && !p_fin) val = new_tok;
        tok_o[m] = val;
    }
    for (int m = t; m < BS*H; m += 256) {
        int nb = m / H, j = m % H;
        int parent = sel[nb] >> 3;
        h[m] = hcT[(size_t)j*8 + parent];
    }
}

// ---------------- finalize ----------------
__global__ void k_final(const float* cum, const int* len, const int* fin,
                        const int* tok, float* out)
{
    int t = threadIdx.x;
    __shared__ int bestIdx;
    if (t == 0) {
        bool anyf = false;
        for (int b = 0; b < BS; ++b) anyf = anyf || (fin[b] != 0);
        float bestv = -3.4e38f; int bi_ = 0;
        for (int b = 0; b < BS; ++b) {
            float sc = cum[b] / (float)len[b];
            float adj = anyf ? (fin[b] ? sc : NEGV) : sc;
            if (adj > bestv) { bestv = adj; bi_ = b; }
        }
        bestIdx = bi_;
        out[T] = cum[bi_] / (float)len[bi_];
    }
    __syncthreads();
    if (t < T) out[t] = (float)tok[bestIdx*T + t];
}

extern "C" void kernel_launch(void* const* d_in, const int* in_sizes, int n_in,
                              void* d_out, int out_size, void* d_ws, size_t ws_size,
                              hipStream_t stream) {
    const float* emb  = (const float*)d_in[0];
    const float* Wx   = (const float*)d_in[1];
    const float* Wh   = (const float*)d_in[2];
    const float* Wout = (const float*)d_in[3];
    const float* bout = (const float*)d_in[4];
    const float* enc  = (const float*)d_in[5];
    const float* h0   = (const float*)d_in[6];
    float* out = (float*)d_out;

    // ws-size markers: show up in rocprof dispatch list, tell us next round
    // whether a compressed-weight (bf16 ~197 MiB / fp8 ~103 MiB) path is feasible.
    if (ws_size >= (size_t) 32*1024*1024) k_ws_ge_032mb<<<1, 64, 0, stream>>>();
    if (ws_size >= (size_t) 64*1024*1024) k_ws_ge_064mb<<<1, 64, 0, stream>>>();
    if (ws_size >= (size_t)128*1024*1024) k_ws_ge_128mb<<<1, 64, 0, stream>>>();
    if (ws_size >= (size_t)210*1024*1024) k_ws_ge_210mb<<<1, 64, 0, stream>>>();
    if (ws_size >= (size_t)256*1024*1024) k_ws_ge_256mb<<<1, 64, 0, stream>>>();
    if (ws_size >= (size_t)384*1024*1024) k_ws_ge_384mb<<<1, 64, 0, stream>>>();
    if (ws_size >= (size_t)512*1024*1024) k_ws_ge_512mb<<<1, 64, 0, stream>>>();

    char* w = (char*)d_ws;
    auto alloc = [&](size_t bytes) -> char* {
        char* p = w; w += (bytes + 255) & ~(size_t)255; return p;
    };

    float* h      = (float*)alloc((size_t)BS*H*4);
    float* hcT    = (float*)alloc((size_t)2*H*BS*4);
    float* part   = (float*)alloc((size_t)KS*4*BS*H*4);        // 2 MiB
    float* cumb0  = (float*)alloc(8*4);
    float* cumb1  = (float*)alloc(8*4);
    int* lenb0 = (int*)alloc(8*4);
    int* lenb1 = (int*)alloc(8*4);
    int* finb0 = (int*)alloc(8*4);
    int* finb1 = (int*)alloc(8*4);
    int* latb0 = (int*)alloc(8*4);
    int* latb1 = (int*)alloc(8*4);
    int* tokb0 = (int*)alloc((size_t)BS*T*4);
    int* tokb1 = (int*)alloc((size_t)BS*T*4);

    float* lpart  = (float*)alloc((size_t)8*BS*V*4);           // 12.87 MiB
    float* cand_v = (float*)alloc(8*8*8*4);
    int*   cand_i = (int*)  alloc(8*8*8*4);
    float* cm     = (float*)alloc(64*4);
    float* clp    = (float*)alloc(64*4);

    float* cumb[2] = {cumb0, cumb1};
    int*   lenb[2] = {lenb0, lenb1};
    int*   finb[2] = {finb0, finb1};
    int*   latb[2] = {latb0, latb1};
    int*   tokb[2] = {tokb0, tokb1};

    k_init<<<1, 256, 0, stream>>>(h0, h, cumb[0], lenb[0], finb[0], latb[0], tokb[0]);

    for (int s = 0; s < T; ++s) {
        int p = s & 1, q = 1 - p;
        k_gru_part<<<dim3(4, KS), 256, 0, stream>>>(emb, Wx, Wh, h, latb[p], part);
        k_gate_attn<<<BS, 256, 0, stream>>>(part, h, enc, hcT);
        k_gemv_part<<<dim3(CB, 8), 256, 0, stream>>>(Wout, hcT, lpart);
        k_topk_part<<<dim3(BS, 8), 256, 0, stream>>>(lpart, bout, cand_v, cand_i, cm, clp);
        k_merge_update_fb<<<1, 256, 0, stream>>>(cand_v, cand_i, cm, clp,
                                                 cumb[p], lenb[p], finb[p], latb[p], tokb[p],
                                                 cumb[q], lenb[q], finb[q], latb[q], tokb[q],
                                                 hcT, h, s);
    }
    k_final<<<1, 64, 0, stream>>>(cumb[0], lenb[0], finb[0], tokb[0], out);
}